// Round 4
// baseline (326.880 us; speedup 1.0000x reference)
//
#include <hip/hip_runtime.h>
#include <stdint.h>

typedef __bf16 bf16x8 __attribute__((ext_vector_type(8)));
typedef float f32x4 __attribute__((ext_vector_type(4)));

__device__ __forceinline__ unsigned short f2bf(float f) {
    union { float f; unsigned u; } x; x.f = f;
    unsigned u = x.u;
    u += 0x7FFFu + ((u >> 16) & 1u);   // round-to-nearest-even
    return (unsigned short)(u >> 16);
}
__device__ __forceinline__ unsigned pack2(float lo, float hi) {
    return ((unsigned)f2bf(hi) << 16) | (unsigned)f2bf(lo);
}
union U16 { uint4 u; bf16x8 v; };

// ---------------- Yt = (X @ W + b)^T  as bf16 [64][8192], layer 1 only ----------------
template <int CIN>
__global__ __launch_bounds__(256) void small_gemm(const float* __restrict__ X,
                                                  const float* __restrict__ W,
                                                  const float* __restrict__ b,
                                                  int cout,
                                                  unsigned short* __restrict__ Yt) {
    __shared__ float Xs[32 * (CIN + 1)];
    __shared__ float Ws[CIN * 64];
    __shared__ float bs[64];
    const int t = threadIdx.x;
    const int i0 = blockIdx.x * 32;

    for (int e = t; e < 32 * CIN; e += 256) {
        int r = e / CIN, c = e % CIN;
        Xs[r * (CIN + 1) + c] = X[(size_t)(i0 + r) * CIN + c];
    }
    for (int e = t; e < CIN * 64; e += 256) {
        int k = e >> 6, j = e & 63;
        Ws[e] = (j < cout) ? W[k * cout + j] : 0.0f;
    }
    if (t < 64) bs[t] = (t < cout) ? b[t] : 0.0f;
    __syncthreads();

    const int i = t & 31;
    const int jg = t >> 5;
    float acc[8];
#pragma unroll
    for (int jj = 0; jj < 8; ++jj) acc[jj] = 0.0f;

    for (int k = 0; k < CIN; ++k) {
        float xv = Xs[i * (CIN + 1) + k];
        const float4* wr = (const float4*)&Ws[k * 64 + jg * 8];
        float4 w0 = wr[0], w1 = wr[1];
        acc[0] += xv * w0.x; acc[1] += xv * w0.y;
        acc[2] += xv * w0.z; acc[3] += xv * w0.w;
        acc[4] += xv * w1.x; acc[5] += xv * w1.y;
        acc[6] += xv * w1.z; acc[7] += xv * w1.w;
    }
#pragma unroll
    for (int jj = 0; jj < 8; ++jj) {
        int j = jg * 8 + jj;
        Yt[(size_t)j * 8192 + i0 + i] = f2bf(acc[jj] + bs[j]);
    }
}

// ---------------- big GEMM, LDS-free: P[ks] = A[rows,kslice] @ Y[kslice,64] ----------
// BM=64, BN=64, 4 waves (2M x 2N), split-K = 8 -> grid 128x8 = 1024 blocks.
// NO LDS, NO barriers: A and B fragments loaded straight from global in MFMA
// fragment layout (per-lane 16B chunks, 64B-coalesced); register ping-pong
// double-buffer; compiler-counted vmcnt only — no vmcnt(0) drains in the loop.
// CONV=1: A read fp32, cvt in regs, wn==0 waves store bf16 copy to Ab.
// CONV=0: A read bf16 from Ab (L3-resident).
template <int CONV>
__global__ __launch_bounds__(256, CONV ? 3 : 4)
void big_gemm(const float* __restrict__ Afp,
              unsigned short* __restrict__ Ab,
              const unsigned short* __restrict__ Yt,
              float* __restrict__ P) {
    const int t = threadIdx.x;
    const int lane = t & 63, wid = t >> 6;
    const int lane15 = lane & 15, lane4 = lane >> 4;
    const int wm = wid >> 1, wn = wid & 1;
    const int row0 = blockIdx.x * 64;
    const int kbase = blockIdx.y * 1024;   // split-K = 8
    const int arow = row0 + wm * 32 + lane15;  // + m*16
    const int brow = wn * 32 + lane15;         // + n*16
    const int kc = lane4 * 8;                  // + ks*32

    f32x4 acc[2][2];
    const f32x4 z4 = {0.f, 0.f, 0.f, 0.f};
#pragma unroll
    for (int m = 0; m < 2; ++m)
#pragma unroll
        for (int n = 0; n < 2; ++n) acc[m][n] = z4;

    auto loadB = [&](bf16x8 (&bb)[2][2], int kt) {
#pragma unroll
        for (int n = 0; n < 2; ++n)
#pragma unroll
            for (int ks = 0; ks < 2; ++ks)
                bb[n][ks] = *(const bf16x8*)(Yt + (size_t)(brow + n * 16) * 8192 +
                                             kt + ks * 32 + kc);
    };

    if constexpr (CONV) {
        auto loadT = [&](float4 (&ra)[2][2][2], bf16x8 (&bb)[2][2], int kt) {
#pragma unroll
            for (int m = 0; m < 2; ++m)
#pragma unroll
                for (int ks = 0; ks < 2; ++ks) {
                    const float* gp = Afp + (size_t)(arow + m * 16) * 8192 +
                                      kt + ks * 32 + kc;
                    ra[m][ks][0] = *(const float4*)gp;
                    ra[m][ks][1] = *(const float4*)(gp + 4);
                }
            loadB(bb, kt);
        };
        auto comp = [&](float4 (&ra)[2][2][2], bf16x8 (&bb)[2][2], int kt) {
#pragma unroll
            for (int ks = 0; ks < 2; ++ks) {
                bf16x8 af[2];
#pragma unroll
                for (int m = 0; m < 2; ++m) {
                    U16 u;
                    u.u.x = pack2(ra[m][ks][0].x, ra[m][ks][0].y);
                    u.u.y = pack2(ra[m][ks][0].z, ra[m][ks][0].w);
                    u.u.z = pack2(ra[m][ks][1].x, ra[m][ks][1].y);
                    u.u.w = pack2(ra[m][ks][1].z, ra[m][ks][1].w);
                    af[m] = u.v;
                    if (wn == 0)
                        *(uint4*)(Ab + (size_t)(arow + m * 16) * 8192 +
                                  kt + ks * 32 + kc) = u.u;
                }
#pragma unroll
                for (int m = 0; m < 2; ++m)
#pragma unroll
                    for (int n = 0; n < 2; ++n)
                        acc[m][n] = __builtin_amdgcn_mfma_f32_16x16x32_bf16(
                            af[m], bb[n][ks], acc[m][n], 0, 0, 0);
            }
        };
        float4 raA[2][2][2], raB[2][2][2];
        bf16x8 bbA[2][2], bbB[2][2];
        loadT(raA, bbA, kbase);
        for (int tt = 0; tt < 16; tt += 2) {
            if (tt + 1 < 16) loadT(raB, bbB, kbase + (tt + 1) * 64);
            comp(raA, bbA, kbase + tt * 64);
            if (tt + 2 < 16) loadT(raA, bbA, kbase + (tt + 2) * 64);
            if (tt + 1 < 16) comp(raB, bbB, kbase + (tt + 1) * 64);
        }
    } else {
        auto loadT = [&](bf16x8 (&aa)[2][2], bf16x8 (&bb)[2][2], int kt) {
#pragma unroll
            for (int m = 0; m < 2; ++m)
#pragma unroll
                for (int ks = 0; ks < 2; ++ks)
                    aa[m][ks] = *(const bf16x8*)(Ab + (size_t)(arow + m * 16) * 8192 +
                                                 kt + ks * 32 + kc);
            loadB(bb, kt);
        };
        auto comp = [&](bf16x8 (&aa)[2][2], bf16x8 (&bb)[2][2]) {
#pragma unroll
            for (int ks = 0; ks < 2; ++ks)
#pragma unroll
                for (int m = 0; m < 2; ++m)
#pragma unroll
                    for (int n = 0; n < 2; ++n)
                        acc[m][n] = __builtin_amdgcn_mfma_f32_16x16x32_bf16(
                            aa[m][ks], bb[n][ks], acc[m][n], 0, 0, 0);
        };
        bf16x8 aaA[2][2], aaB[2][2], bbA[2][2], bbB[2][2];
        loadT(aaA, bbA, kbase);
        for (int tt = 0; tt < 16; tt += 2) {
            if (tt + 1 < 16) loadT(aaB, bbB, kbase + (tt + 1) * 64);
            comp(aaA, bbA);
            if (tt + 2 < 16) loadT(aaA, bbA, kbase + (tt + 2) * 64);
            if (tt + 1 < 16) comp(aaB, bbB);
        }
    }

    // C/D layout: col = lane&15, row = (lane>>4)*4 + q
    float* Po = P + (size_t)blockIdx.y * (8192 * 64);
#pragma unroll
    for (int m = 0; m < 2; ++m) {
        int r = row0 + wm * 32 + m * 16 + lane4 * 4;
#pragma unroll
        for (int n = 0; n < 2; ++n) {
            int cc = wn * 32 + n * 16 + lane15;
#pragma unroll
            for (int q = 0; q < 4; ++q)
                Po[(size_t)(r + q) * 64 + cc] = acc[m][n][q];
        }
    }
}

// ---------------- fused: reduce split-K + poly + next layer's small GEMM ----------------
// MODE 0: X1 = poly(z); store X1; Yt = (X1 Wn + bn)^T
// MODE 1: v = X1 + poly(z); Yt = (v Wn + bn)^T     (X2 never materialized)
template <int MODE>
__global__ __launch_bounds__(256) void fused_reduce(const float* __restrict__ P,
                                                    const float* __restrict__ cf,
                                                    const float* __restrict__ Wn,
                                                    const float* __restrict__ bn,
                                                    int cout,
                                                    float* __restrict__ X1,
                                                    unsigned short* __restrict__ Yt) {
    __shared__ float Xs[64 * 33];   // [j][i]
    __shared__ float Ws[64 * 64];
    __shared__ float bs[64];
    const int t = threadIdx.x;
    const int i0 = blockIdx.x * 32;
    const int NT4 = 8192 * 64 / 4;
    const float4* P4 = (const float4*)P;
    float4* X14 = (float4*)X1;

    for (int e = t; e < 64 * 64; e += 256) {
        int k = e >> 6, j = e & 63;
        Ws[e] = (j < cout) ? Wn[k * cout + j] : 0.0f;
    }
    if (t < 64) bs[t] = (t < cout) ? bn[t] : 0.0f;
    const float c0 = cf[0], c1 = cf[1], c2 = cf[2];

#pragma unroll
    for (int s = 0; s < 2; ++s) {
        int e4 = s * 256 + t;          // 512 float4 = 32 rows x 16
        int i = e4 >> 4, jc = e4 & 15;
        int base4 = (i0 + i) * 16 + jc;
        float4 z = {0.f, 0.f, 0.f, 0.f};
#pragma unroll
        for (int ks = 0; ks < 8; ++ks) {
            float4 p = P4[(size_t)ks * NT4 + base4];
            z.x += p.x; z.y += p.y; z.z += p.z; z.w += p.w;
        }
        float4 v;
        v.x = z.x * (c0 + z.x * (c1 + z.x * c2));
        v.y = z.y * (c0 + z.y * (c1 + z.y * c2));
        v.z = z.z * (c0 + z.z * (c1 + z.z * c2));
        v.w = z.w * (c0 + z.w * (c1 + z.w * c2));
        if (MODE == 0) {
            X14[base4] = v;
        } else {
            float4 xr = X14[base4];
            v.x += xr.x; v.y += xr.y; v.z += xr.z; v.w += xr.w;
        }
        Xs[(jc * 4 + 0) * 33 + i] = v.x;
        Xs[(jc * 4 + 1) * 33 + i] = v.y;
        Xs[(jc * 4 + 2) * 33 + i] = v.z;
        Xs[(jc * 4 + 3) * 33 + i] = v.w;
    }
    __syncthreads();

    const int i = t & 31;
    const int jg = t >> 5;
    float acc[8];
#pragma unroll
    for (int jj = 0; jj < 8; ++jj) acc[jj] = 0.0f;
    for (int k = 0; k < 64; ++k) {
        float xv = Xs[k * 33 + i];
        const float4* wr = (const float4*)&Ws[k * 64 + jg * 8];
        float4 w0 = wr[0], w1 = wr[1];
        acc[0] += xv * w0.x; acc[1] += xv * w0.y;
        acc[2] += xv * w0.z; acc[3] += xv * w0.w;
        acc[4] += xv * w1.x; acc[5] += xv * w1.y;
        acc[6] += xv * w1.z; acc[7] += xv * w1.w;
    }
#pragma unroll
    for (int jj = 0; jj < 8; ++jj) {
        int j = jg * 8 + jj;
        Yt[(size_t)j * 8192 + i0 + i] = f2bf(acc[jj] + bs[j]);
    }
}

// ---------------- final: reduce + poly -> out [8192 x 40], float4 ----------------
__global__ void reduce_out(const float* __restrict__ P, const float* __restrict__ cf,
                           float* __restrict__ out) {
    int e4 = blockIdx.x * 256 + threadIdx.x;   // < 131072
    const int NT4 = 8192 * 64 / 4;
    const float4* P4 = (const float4*)P;
    float4 z = {0.f, 0.f, 0.f, 0.f};
#pragma unroll
    for (int ks = 0; ks < 8; ++ks) {
        float4 p = P4[(size_t)ks * NT4 + e4];
        z.x += p.x; z.y += p.y; z.z += p.z; z.w += p.w;
    }
    float c0 = cf[0], c1 = cf[1], c2 = cf[2];
    float4 v;
    v.x = z.x * (c0 + z.x * (c1 + z.x * c2));
    v.y = z.y * (c0 + z.y * (c1 + z.y * c2));
    v.z = z.z * (c0 + z.z * (c1 + z.z * c2));
    v.w = z.w * (c0 + z.w * (c1 + z.w * c2));
    int i = e4 >> 4, jc = e4 & 15;
    if (jc < 10) ((float4*)out)[i * 10 + jc] = v;   // 40 cols = 10 float4
}

extern "C" void kernel_launch(void* const* d_in, const int* in_sizes, int n_in,
                              void* d_out, int out_size, void* d_ws, size_t ws_size,
                              hipStream_t stream) {
    const float* nf   = (const float*)d_in[0];
    const float* Amat = (const float*)d_in[1];
    const float* W1   = (const float*)d_in[2];
    const float* b1   = (const float*)d_in[3];
    const float* c1   = (const float*)d_in[4];
    const float* W2   = (const float*)d_in[5];
    const float* b2   = (const float*)d_in[6];
    const float* c2   = (const float*)d_in[7];
    const float* W3   = (const float*)d_in[8];
    const float* b3   = (const float*)d_in[9];
    const float* c3   = (const float*)d_in[10];
    float* out = (float*)d_out;

    char* ws = (char*)d_ws;
    unsigned short* Abf = (unsigned short*)(ws);                 // 134217728 B
    unsigned short* Yt  = (unsigned short*)(ws + 134217728);     //   1048576 B
    float* X1           = (float*)(ws + 135266304);              //   2097152 B
    float* Pp           = (float*)(ws + 137363456);              //  16777216 B
    // total: 154140672 B

    // layer 1 (fused A-conversion: writes Abf for layers 2/3)
    small_gemm<128><<<256, 256, 0, stream>>>(nf, W1, b1, 64, Yt);
    big_gemm<1><<<dim3(128, 8), 256, 0, stream>>>(Amat, Abf, Yt, Pp);
    fused_reduce<0><<<256, 256, 0, stream>>>(Pp, c1, W2, b2, 64, X1, Yt);

    // layer 2 (residual folded into fused_reduce<1>)
    big_gemm<0><<<dim3(128, 8), 256, 0, stream>>>(nullptr, Abf, Yt, Pp);
    fused_reduce<1><<<256, 256, 0, stream>>>(Pp, c2, W3, b3, 40, X1, Yt);

    // layer 3
    big_gemm<0><<<dim3(128, 8), 256, 0, stream>>>(nullptr, Abf, Yt, Pp);
    reduce_out<<<512, 256, 0, stream>>>(Pp, c3, out);
}

// Round 5
// 204.010 us; speedup vs baseline: 1.6023x; 1.6023x over previous
//
#include <hip/hip_runtime.h>
#include <stdint.h>

typedef __bf16 bf16x8 __attribute__((ext_vector_type(8)));
typedef float f32x4 __attribute__((ext_vector_type(4)));

using gvoid = const __attribute__((address_space(1))) void;
using lvoid = __attribute__((address_space(3))) void;

__device__ __forceinline__ unsigned short f2bf(float f) {
    union { float f; unsigned u; } x; x.f = f;
    unsigned u = x.u;
    u += 0x7FFFu + ((u >> 16) & 1u);   // round-to-nearest-even
    return (unsigned short)(u >> 16);
}
__device__ __forceinline__ unsigned pack2(float lo, float hi) {
    return ((unsigned)f2bf(hi) << 16) | (unsigned)f2bf(lo);
}

// ---------------- A fp32 -> bf16, streaming (8 floats/thread/iter) ----------------
__global__ __launch_bounds__(256) void convert_bf16(const float* __restrict__ in,
                                                    unsigned short* __restrict__ out,
                                                    int n8) {
    int idx = blockIdx.x * 256 + threadIdx.x;
    int stride = gridDim.x * 256;
    const float4* in4 = (const float4*)in;
    uint4* out8 = (uint4*)out;
    for (int i = idx; i < n8; i += stride) {
        float4 a = in4[2 * i], b = in4[2 * i + 1];
        uint4 o;
        o.x = pack2(a.x, a.y);
        o.y = pack2(a.z, a.w);
        o.z = pack2(b.x, b.y);
        o.w = pack2(b.z, b.w);
        out8[i] = o;
    }
}

// ---------------- Yt = (X @ W + b)^T  as bf16 [64][8192], layer 1 only ----------------
template <int CIN>
__global__ __launch_bounds__(256) void small_gemm(const float* __restrict__ X,
                                                  const float* __restrict__ W,
                                                  const float* __restrict__ b,
                                                  int cout,
                                                  unsigned short* __restrict__ Yt) {
    __shared__ float Xs[32 * (CIN + 1)];
    __shared__ float Ws[CIN * 64];
    __shared__ float bs[64];
    const int t = threadIdx.x;
    const int i0 = blockIdx.x * 32;

    for (int e = t; e < 32 * CIN; e += 256) {
        int r = e / CIN, c = e % CIN;
        Xs[r * (CIN + 1) + c] = X[(size_t)(i0 + r) * CIN + c];
    }
    for (int e = t; e < CIN * 64; e += 256) {
        int k = e >> 6, j = e & 63;
        Ws[e] = (j < cout) ? W[k * cout + j] : 0.0f;
    }
    if (t < 64) bs[t] = (t < cout) ? b[t] : 0.0f;
    __syncthreads();

    const int i = t & 31;
    const int jg = t >> 5;
    float acc[8];
#pragma unroll
    for (int jj = 0; jj < 8; ++jj) acc[jj] = 0.0f;

    for (int k = 0; k < CIN; ++k) {
        float xv = Xs[i * (CIN + 1) + k];
        const float4* wr = (const float4*)&Ws[k * 64 + jg * 8];
        float4 w0 = wr[0], w1 = wr[1];
        acc[0] += xv * w0.x; acc[1] += xv * w0.y;
        acc[2] += xv * w0.z; acc[3] += xv * w0.w;
        acc[4] += xv * w1.x; acc[5] += xv * w1.y;
        acc[6] += xv * w1.z; acc[7] += xv * w1.w;
    }
#pragma unroll
    for (int jj = 0; jj < 8; ++jj) {
        int j = jg * 8 + jj;
        Yt[(size_t)j * 8192 + i0 + i] = f2bf(acc[jj] + bs[j]);
    }
}

// ---------------- big GEMM: P[ks] = Abf[rows,kslice] @ Y[kslice,64] ----------------
// BM=64, BN=64, BK=64, 4 waves (2M x 2N), split-K = 8 -> 1024 blocks (4/CU).
// global_load_lds staging, double-buffered LDS, XOR swizzle (source-side inverse,
// linear LDS dest). T4 counted-vmcnt: raw s_barrier with s_waitcnt vmcnt(4) so the
// next tile's 4 staged loads stay in flight across the barrier (never drain to 0
// in the main loop). All waves symmetric: own-vmcnt wait THEN barrier => race-free.
__global__ __launch_bounds__(256, 4)
void big_gemm(const unsigned short* __restrict__ Ab,
              const unsigned short* __restrict__ Yt,
              float* __restrict__ P) {
    __shared__ unsigned short As[2][64 * 64];  // 2 x 8 KB
    __shared__ unsigned short Bs[2][64 * 64];  // 2 x 8 KB
    const int t = threadIdx.x;
    const int lane = t & 63, wid = t >> 6;
    const int lane15 = lane & 15, lane4 = lane >> 4;
    const int wm = wid >> 1, wn = wid & 1;
    const int row0 = blockIdx.x * 64;
    const int kbase = blockIdx.y * 1024;   // split-K = 8

    f32x4 acc[2][2];
    const f32x4 z4 = {0.f, 0.f, 0.f, 0.f};
#pragma unroll
    for (int m = 0; m < 2; ++m)
#pragma unroll
        for (int n = 0; n < 2; ++n) acc[m][n] = z4;

    auto stage = [&](int nb, int kt) {
        // A tile: 64 rows x 64 k -> 512 16B chunks, 2 gload_lds rounds
#pragma unroll
        for (int ii = 0; ii < 2; ++ii) {
            int p = ii * 256 + wid * 64 + lane;
            int r = p >> 3;
            int c = (p & 7) ^ (r & 7);  // inverse swizzle on source, linear dest
            const unsigned short* gp = Ab + (size_t)(row0 + r) * 8192 + (kt + c * 8);
            unsigned short* lp = &As[nb][(ii * 256 + wid * 64) * 8];
            __builtin_amdgcn_global_load_lds((gvoid*)gp, (lvoid*)lp, 16, 0, 0);
        }
        // B tile: 64 n x 64 k -> 512 chunks, 2 rounds
#pragma unroll
        for (int ii = 0; ii < 2; ++ii) {
            int q = ii * 256 + wid * 64 + lane;
            int n = q >> 3;
            int c = (q & 7) ^ (n & 7);
            const unsigned short* gp = Yt + (size_t)n * 8192 + (kt + c * 8);
            unsigned short* lp = &Bs[nb][(ii * 256 + wid * 64) * 8];
            __builtin_amdgcn_global_load_lds((gvoid*)gp, (lvoid*)lp, 16, 0, 0);
        }
    };

    stage(0, kbase);
    int buf = 0;
    for (int tt = 0; tt < 16; ++tt) {
        if (tt + 1 < 16) {
            stage(buf ^ 1, kbase + (tt + 1) * 64);
            // tile-t's 4 loads done (4 newest = t+1's stay in flight), then barrier
            asm volatile("s_waitcnt vmcnt(4)\n\ts_barrier" ::: "memory");
        } else {
            asm volatile("s_waitcnt vmcnt(0)\n\ts_barrier" ::: "memory");
        }
#pragma unroll
        for (int ks = 0; ks < 2; ++ks) {
            bf16x8 af[2], bfr[2];
#pragma unroll
            for (int m = 0; m < 2; ++m) {
                int r = wm * 32 + m * 16 + lane15;
                int c = ks * 4 + lane4;
                af[m] = *(const bf16x8*)&As[buf][((r << 3) | (c ^ (r & 7))) << 3];
            }
#pragma unroll
            for (int n = 0; n < 2; ++n) {
                int rn = wn * 32 + n * 16 + lane15;
                int c = ks * 4 + lane4;
                bfr[n] = *(const bf16x8*)&Bs[buf][((rn << 3) | (c ^ (rn & 7))) << 3];
            }
#pragma unroll
            for (int m = 0; m < 2; ++m)
#pragma unroll
                for (int n = 0; n < 2; ++n)
                    acc[m][n] = __builtin_amdgcn_mfma_f32_16x16x32_bf16(
                        af[m], bfr[n], acc[m][n], 0, 0, 0);
        }
        // all my ds_reads consumed by MFMA (lgkm drained by compiler) -> safe to
        // let other waves' next-tile gload_lds overwrite buf after this barrier
        asm volatile("s_barrier" ::: "memory");
        buf ^= 1;
    }

    // C/D layout: col = lane&15, row = (lane>>4)*4 + q
    float* Po = P + (size_t)blockIdx.y * (8192 * 64);
#pragma unroll
    for (int m = 0; m < 2; ++m) {
        int r = row0 + wm * 32 + m * 16 + lane4 * 4;
#pragma unroll
        for (int n = 0; n < 2; ++n) {
            int cc = wn * 32 + n * 16 + lane15;
#pragma unroll
            for (int q = 0; q < 4; ++q)
                Po[(size_t)(r + q) * 64 + cc] = acc[m][n][q];
        }
    }
}

// ---------------- fused: reduce split-K + poly + next layer's small GEMM ----------------
// MODE 0: X1 = poly(z); store X1; Yt = (X1 Wn + bn)^T
// MODE 1: v = X1 + poly(z); Yt = (v Wn + bn)^T     (X2 never materialized)
template <int MODE>
__global__ __launch_bounds__(256) void fused_reduce(const float* __restrict__ P,
                                                    const float* __restrict__ cf,
                                                    const float* __restrict__ Wn,
                                                    const float* __restrict__ bn,
                                                    int cout,
                                                    float* __restrict__ X1,
                                                    unsigned short* __restrict__ Yt) {
    __shared__ float Xs[64 * 33];   // [j][i]
    __shared__ float Ws[64 * 64];
    __shared__ float bs[64];
    const int t = threadIdx.x;
    const int i0 = blockIdx.x * 32;
    const int NT4 = 8192 * 64 / 4;
    const float4* P4 = (const float4*)P;
    float4* X14 = (float4*)X1;

    for (int e = t; e < 64 * 64; e += 256) {
        int k = e >> 6, j = e & 63;
        Ws[e] = (j < cout) ? Wn[k * cout + j] : 0.0f;
    }
    if (t < 64) bs[t] = (t < cout) ? bn[t] : 0.0f;
    const float c0 = cf[0], c1 = cf[1], c2 = cf[2];

#pragma unroll
    for (int s = 0; s < 2; ++s) {
        int e4 = s * 256 + t;          // 512 float4 = 32 rows x 16
        int i = e4 >> 4, jc = e4 & 15;
        int base4 = (i0 + i) * 16 + jc;
        float4 z = {0.f, 0.f, 0.f, 0.f};
#pragma unroll
        for (int ks = 0; ks < 8; ++ks) {
            float4 p = P4[(size_t)ks * NT4 + base4];
            z.x += p.x; z.y += p.y; z.z += p.z; z.w += p.w;
        }
        float4 v;
        v.x = z.x * (c0 + z.x * (c1 + z.x * c2));
        v.y = z.y * (c0 + z.y * (c1 + z.y * c2));
        v.z = z.z * (c0 + z.z * (c1 + z.z * c2));
        v.w = z.w * (c0 + z.w * (c1 + z.w * c2));
        if (MODE == 0) {
            X14[base4] = v;
        } else {
            float4 xr = X14[base4];
            v.x += xr.x; v.y += xr.y; v.z += xr.z; v.w += xr.w;
        }
        Xs[(jc * 4 + 0) * 33 + i] = v.x;
        Xs[(jc * 4 + 1) * 33 + i] = v.y;
        Xs[(jc * 4 + 2) * 33 + i] = v.z;
        Xs[(jc * 4 + 3) * 33 + i] = v.w;
    }
    __syncthreads();

    const int i = t & 31;
    const int jg = t >> 5;
    float acc[8];
#pragma unroll
    for (int jj = 0; jj < 8; ++jj) acc[jj] = 0.0f;
    for (int k = 0; k < 64; ++k) {
        float xv = Xs[k * 33 + i];
        const float4* wr = (const float4*)&Ws[k * 64 + jg * 8];
        float4 w0 = wr[0], w1 = wr[1];
        acc[0] += xv * w0.x; acc[1] += xv * w0.y;
        acc[2] += xv * w0.z; acc[3] += xv * w0.w;
        acc[4] += xv * w1.x; acc[5] += xv * w1.y;
        acc[6] += xv * w1.z; acc[7] += xv * w1.w;
    }
#pragma unroll
    for (int jj = 0; jj < 8; ++jj) {
        int j = jg * 8 + jj;
        Yt[(size_t)j * 8192 + i0 + i] = f2bf(acc[jj] + bs[j]);
    }
}

// ---------------- final: reduce + poly -> out [8192 x 40], float4 ----------------
__global__ void reduce_out(const float* __restrict__ P, const float* __restrict__ cf,
                           float* __restrict__ out) {
    int e4 = blockIdx.x * 256 + threadIdx.x;   // < 131072
    const int NT4 = 8192 * 64 / 4;
    const float4* P4 = (const float4*)P;
    float4 z = {0.f, 0.f, 0.f, 0.f};
#pragma unroll
    for (int ks = 0; ks < 8; ++ks) {
        float4 p = P4[(size_t)ks * NT4 + e4];
        z.x += p.x; z.y += p.y; z.z += p.z; z.w += p.w;
    }
    float c0 = cf[0], c1 = cf[1], c2 = cf[2];
    float4 v;
    v.x = z.x * (c0 + z.x * (c1 + z.x * c2));
    v.y = z.y * (c0 + z.y * (c1 + z.y * c2));
    v.z = z.z * (c0 + z.z * (c1 + z.z * c2));
    v.w = z.w * (c0 + z.w * (c1 + z.w * c2));
    int i = e4 >> 4, jc = e4 & 15;
    if (jc < 10) ((float4*)out)[i * 10 + jc] = v;   // 40 cols = 10 float4
}

extern "C" void kernel_launch(void* const* d_in, const int* in_sizes, int n_in,
                              void* d_out, int out_size, void* d_ws, size_t ws_size,
                              hipStream_t stream) {
    const float* nf   = (const float*)d_in[0];
    const float* Amat = (const float*)d_in[1];
    const float* W1   = (const float*)d_in[2];
    const float* b1   = (const float*)d_in[3];
    const float* c1   = (const float*)d_in[4];
    const float* W2   = (const float*)d_in[5];
    const float* b2   = (const float*)d_in[6];
    const float* c2   = (const float*)d_in[7];
    const float* W3   = (const float*)d_in[8];
    const float* b3   = (const float*)d_in[9];
    const float* c3   = (const float*)d_in[10];
    float* out = (float*)d_out;

    char* ws = (char*)d_ws;
    unsigned short* Abf = (unsigned short*)(ws);                 // 134217728 B
    unsigned short* Yt  = (unsigned short*)(ws + 134217728);     //   1048576 B
    float* X1           = (float*)(ws + 135266304);              //   2097152 B
    float* Pp           = (float*)(ws + 137363456);              //  16777216 B
    // total: 154140672 B

    // streaming conversion (HBM-bound, ~86% peak) + layer-1 feature transform
    convert_bf16<<<2048, 256, 0, stream>>>(Amat, Abf, 8192 * 8192 / 8);
    small_gemm<128><<<256, 256, 0, stream>>>(nf, W1, b1, 64, Yt);

    // layer 1
    big_gemm<<<dim3(128, 8), 256, 0, stream>>>(Abf, Yt, Pp);
    fused_reduce<0><<<256, 256, 0, stream>>>(Pp, c1, W2, b2, 64, X1, Yt);

    // layer 2 (residual folded into fused_reduce<1>)
    big_gemm<<<dim3(128, 8), 256, 0, stream>>>(Abf, Yt, Pp);
    fused_reduce<1><<<256, 256, 0, stream>>>(Pp, c2, W3, b3, 40, X1, Yt);

    // layer 3
    big_gemm<<<dim3(128, 8), 256, 0, stream>>>(Abf, Yt, Pp);
    reduce_out<<<512, 256, 0, stream>>>(Pp, c3, out);
}